// Round 3
// baseline (181.266 us; speedup 1.0000x reference)
//
#include <hip/hip_runtime.h>
#include <math.h>

// Problem dims
#define BB 2048
#define CC 64
#define BERT 768
#define N_CTRY 250
#define N_CODES 654

// ws layout (floats)
#define OFF_PCHAT   0                    // [250][24] normalized country projections
#define OFF_CODEHAT (250*24)             // [654][8]  normalized code embeddings
#define OFF_XALL    (OFF_CODEHAT + 654*8)// [2048][80]: 0-23 x̂, 24-31 x̂code, 32-55 x̂other, 56-79 x̂doc

#define PROJ_BLOCKS (BB / 2)             // 2 rows per block

// ---------------------------------------------------------------------------
// Fused kernel A:
//   blocks [0, 1024)       : per-row projections (2 rows/block) -> xall
//   blocks [1024, 1274)    : country-table projection (1 row/block) -> pchat
//   blocks [1274, 1277)    : code-embedding normalization -> codehat
//
// Register budget is THE constraint (R2 post-mortem: acc[4][20]+wv = 128 ->
// spill cliff, 69 MB scratch traffic). 2 rows/block: acc[2][20]=40 +
// wv[4][3]=48 + addressing ~= 105 VGPRs -> no spill, 4 waves/SIMD.
// ---------------------------------------------------------------------------
__global__ __launch_bounds__(256) void kA_fused(
    const float* __restrict__ place, const float* __restrict__ other,
    const float* __restrict__ doc,
    const float* __restrict__ W_t2c, const float* __restrict__ b_t2c,
    const float* __restrict__ W_code, const float* __restrict__ b_code,
    const float* __restrict__ W_ctx, const float* __restrict__ b_ctx,
    const float* __restrict__ ctab, const float* __restrict__ W_cet,
    const float* __restrict__ b_cet, const float* __restrict__ code_emb,
    float* __restrict__ ws) {
  __shared__ float s_in[6][768];     // [tensor*2 + r][k]   18 KB
  __shared__ float s_proj[2][80];
  __shared__ float s_inv2[2][4];

  const int bid = blockIdx.x;
  const int tid = threadIdx.x;
  const int w = tid >> 6, lane = tid & 63;

  if (bid < PROJ_BLOCKS) {
    // ---------------- per-row projection path ----------------
    float* xall = ws + OFF_XALL;
    const int row0 = bid * 2;

    // stage 6 input rows into LDS, coalesced (1152 float4)
    for (int f = tid; f < 1152; f += 256) {
      const int rowi = f / 192;               // 0..5
      const int col4 = f % 192;
      const int t = rowi >> 1, r = rowi & 1;
      const float* bp = (t == 0) ? place : (t == 1) ? other : doc;
      float4 v = ((const float4*)(bp + (size_t)(row0 + r) * BERT))[col4];
      reinterpret_cast<float4*>(&s_in[0][0])[f] = v;
    }
    __syncthreads();

    float acc[2][20];
#pragma unroll
    for (int r = 0; r < 2; ++r)
#pragma unroll
      for (int jj = 0; jj < 20; ++jj) acc[r][jj] = 0.f;

    const int j0w = w * 20;
#pragma unroll
    for (int g = 0; g < 5; ++g) {
      const int j0 = j0w + g * 4;             // wave-uniform; group boundaries
      const float* wbase;                     // 24/32/56 are multiples of 4
      int jb;
      if (j0 < 24)      { wbase = W_t2c;  jb = j0; }
      else if (j0 < 32) { wbase = W_code; jb = j0 - 24; }
      else if (j0 < 56) { wbase = W_ctx;  jb = j0 - 32; }
      else              { wbase = W_ctx;  jb = j0 - 56; }
      const int t = (j0 < 32) ? 0 : (j0 < 56) ? 1 : 2;

      // hoist this wave's 4 weight rows into registers (48 VGPRs)
      float4 wv[4][3];
#pragma unroll
      for (int u = 0; u < 4; ++u) {
        const float4* wr = (const float4*)(wbase + (size_t)(jb + u) * BERT);
#pragma unroll
        for (int i = 0; i < 3; ++i) wv[u][i] = wr[lane + 64 * i];
      }
#pragma unroll
      for (int i = 0; i < 3; ++i) {
#pragma unroll
        for (int r = 0; r < 2; ++r) {
          float4 a = reinterpret_cast<const float4*>(&s_in[t * 2 + r][0])[lane + 64 * i];
#pragma unroll
          for (int u = 0; u < 4; ++u) {
            acc[r][g * 4 + u] += a.x * wv[u][i].x + a.y * wv[u][i].y +
                                 a.z * wv[u][i].z + a.w * wv[u][i].w;
          }
        }
      }
    }

    // one batched butterfly over all 40 accumulators (independent chains)
#pragma unroll
    for (int s = 32; s >= 1; s >>= 1) {
#pragma unroll
      for (int r = 0; r < 2; ++r)
#pragma unroll
        for (int jj = 0; jj < 20; ++jj)
          acc[r][jj] += __shfl_xor(acc[r][jj], s, 64);
    }

    if (lane == 0) {
#pragma unroll
      for (int jj = 0; jj < 20; ++jj) {
        const int j = j0w + jj;
        const float bias = (j < 24) ? b_t2c[j] : (j < 32) ? b_code[j - 24]
                         : (j < 56) ? b_ctx[j - 32] : b_ctx[j - 56];
#pragma unroll
        for (int r = 0; r < 2; ++r) s_proj[r][j] = acc[r][jj] + bias;
      }
    }
    __syncthreads();

    if (tid < 8) {
      const int r = tid >> 2, g = tid & 3;
      const int st[5] = {0, 24, 32, 56, 80};
      float ss = 0.f;
      for (int k = st[g]; k < st[g + 1]; ++k) ss += s_proj[r][k] * s_proj[r][k];
      s_inv2[r][g] = 1.f / fmaxf(sqrtf(ss), 1e-8f);
    }
    __syncthreads();
    if (tid < 160) {
      const int r = tid / 80, j = tid % 80;
      const int g = (j < 24) ? 0 : (j < 32) ? 1 : (j < 56) ? 2 : 3;
      xall[(size_t)(row0 + r) * 80 + j] = s_proj[r][j] * s_inv2[r][g];
    }
  } else if (bid < PROJ_BLOCKS + N_CTRY) {
    // ---------------- country-table projection path ----------------
    float* pchat = ws + OFF_PCHAT;
    const int b = bid - PROJ_BLOCKS;

    float4 in4[3];
#pragma unroll
    for (int i = 0; i < 3; ++i)
      in4[i] = ((const float4*)(ctab + (size_t)b * BERT))[lane + 64 * i];

    float acc6[6];
#pragma unroll
    for (int jj = 0; jj < 6; ++jj) acc6[jj] = 0.f;
#pragma unroll
    for (int jj = 0; jj < 6; ++jj) {
      const int j = w * 6 + jj;
      const float4* wr = (const float4*)(W_cet + (size_t)j * BERT);
#pragma unroll
      for (int i = 0; i < 3; ++i) {
        float4 wv = wr[lane + 64 * i];
        acc6[jj] += in4[i].x * wv.x + in4[i].y * wv.y + in4[i].z * wv.z + in4[i].w * wv.w;
      }
    }
#pragma unroll
    for (int s = 32; s >= 1; s >>= 1)
#pragma unroll
      for (int jj = 0; jj < 6; ++jj) acc6[jj] += __shfl_xor(acc6[jj], s, 64);

    if (lane == 0) {
#pragma unroll
      for (int jj = 0; jj < 6; ++jj) {
        const int j = w * 6 + jj;
        s_proj[0][j] = acc6[jj] + b_cet[j];
      }
    }
    __syncthreads();
    if (tid == 0) {
      float ss = 0.f;
      for (int k = 0; k < 24; ++k) ss += s_proj[0][k] * s_proj[0][k];
      s_inv2[0][0] = 1.f / fmaxf(sqrtf(ss), 1e-8f);
    }
    __syncthreads();
    if (tid < 24) pchat[b * 24 + tid] = s_proj[0][tid] * s_inv2[0][0];
  } else {
    // ---------------- code-embedding normalization path ----------------
    float* codehat = ws + OFF_CODEHAT;
    const int idx = (bid - PROJ_BLOCKS - N_CTRY) * 256 + tid;
    if (idx < N_CODES) {
      float v[8];
      float ss = 0.f;
#pragma unroll
      for (int k = 0; k < 8; ++k) { v[k] = code_emb[idx * 8 + k]; ss += v[k] * v[k]; }
      const float inv = 1.f / fmaxf(sqrtf(ss), 1e-8f);
#pragma unroll
      for (int k = 0; k < 8; ++k) codehat[idx * 8 + k] = v[k] * inv;
    }
  }
}

// ---------------------------------------------------------------------------
// Kernel 3: per-(b,c) classify. 256 threads = 4 waves = 4 rows; lane = class.
// C = 64 == wave size, so softmax is one wave butterfly.
// ---------------------------------------------------------------------------
__global__ __launch_bounds__(256) void k3_classify(
    const int* __restrict__ fcodes, const int* __restrict__ ccodes,
    const float* __restrict__ gaz,
    const float* __restrict__ W_mix1, const float* __restrict__ b_mix1,
    const float* __restrict__ W_mix2, const float* __restrict__ b_mix2,
    const float* __restrict__ W_last, const float* __restrict__ b_last,
    const float* __restrict__ ws, float* __restrict__ out) {
  const float* pchat   = ws + OFF_PCHAT;
  const float* codehat = ws + OFF_CODEHAT;
  const float* xall    = ws + OFF_XALL;
  const int tid = threadIdx.x;
  const int w = tid >> 6, lane = tid & 63;
  const int row = __builtin_amdgcn_readfirstlane(blockIdx.x * 4 + w);
  const float* xv = xall + (size_t)row * 80;

  const int cidx = ccodes[row * CC + lane];
  const int fidx = fcodes[row * CC + lane];

  float cc[24];
  {
    const float4* p4 = (const float4*)(pchat + cidx * 24);
#pragma unroll
    for (int i = 0; i < 6; ++i) {
      float4 v = p4[i];
      cc[4 * i + 0] = v.x; cc[4 * i + 1] = v.y; cc[4 * i + 2] = v.z; cc[4 * i + 3] = v.w;
    }
  }
  float cd[8];
  {
    const float4* q4 = (const float4*)(codehat + fidx * 8);
#pragma unroll
    for (int i = 0; i < 2; ++i) {
      float4 v = q4[i];
      cd[4 * i + 0] = v.x; cd[4 * i + 1] = v.y; cd[4 * i + 2] = v.z; cd[4 * i + 3] = v.w;
    }
  }

  float sc = 0.f, so = 0.f, sd = 0.f, sq = 0.f;
#pragma unroll
  for (int k = 0; k < 24; ++k) {
    sc += xv[k] * cc[k];
    so += xv[32 + k] * cc[k];
    sd += xv[56 + k] * cc[k];
  }
#pragma unroll
  for (int k = 0; k < 8; ++k) sq += xv[24 + k] * cd[k];

  float f[13];
  f[0] = sc; f[1] = sq; f[2] = so; f[3] = sd;
  {
    const float* g = gaz + (size_t)(row * CC + lane) * 9;
#pragma unroll
    for (int i = 0; i < 9; ++i) f[4 + i] = g[i];
  }

  float h1[24];
#pragma unroll
  for (int j = 0; j < 24; ++j) {
    float a = b_mix1[j];
#pragma unroll
    for (int i = 0; i < 13; ++i) a += W_mix1[j * 13 + i] * f[i];
    h1[j] = 1.f / (1.f + __expf(-a));
  }
  float h2[24];
#pragma unroll
  for (int j = 0; j < 24; ++j) {
    float a = b_mix2[j];
#pragma unroll
    for (int i = 0; i < 24; ++i) a += W_mix2[j * 24 + i] * h1[i];
    h2[j] = 1.f / (1.f + __expf(-a));
  }
  float last = b_last[0];
#pragma unroll
  for (int k = 0; k < 24; ++k) last += W_last[k] * h2[k];

  // softmax across the 64 lanes (classes)
  float m = last;
#pragma unroll
  for (int s = 32; s >= 1; s >>= 1) m = fmaxf(m, __shfl_xor(m, s, 64));
  const float e = __expf(last - m);
  float ssum = e;
#pragma unroll
  for (int s = 32; s >= 1; s >>= 1) ssum += __shfl_xor(ssum, s, 64);
  out[row * CC + lane] = e / ssum;
}

// ---------------------------------------------------------------------------
extern "C" void kernel_launch(void* const* d_in, const int* in_sizes, int n_in,
                              void* d_out, int out_size, void* d_ws, size_t ws_size,
                              hipStream_t stream) {
  const float* place   = (const float*)d_in[0];
  const float* other   = (const float*)d_in[1];
  const float* doc     = (const float*)d_in[2];
  const int*   fcodes  = (const int*)d_in[3];
  const int*   ccodes  = (const int*)d_in[4];
  const float* gaz     = (const float*)d_in[5];
  const float* code_emb= (const float*)d_in[6];
  const float* ctab    = (const float*)d_in[7];
  const float* W_cet   = (const float*)d_in[8];
  const float* b_cet   = (const float*)d_in[9];
  const float* W_t2c   = (const float*)d_in[10];
  const float* b_t2c   = (const float*)d_in[11];
  const float* W_ctx   = (const float*)d_in[12];
  const float* b_ctx   = (const float*)d_in[13];
  const float* W_code  = (const float*)d_in[14];
  const float* b_code  = (const float*)d_in[15];
  const float* W_mix1  = (const float*)d_in[16];
  const float* b_mix1  = (const float*)d_in[17];
  const float* W_mix2  = (const float*)d_in[18];
  const float* b_mix2  = (const float*)d_in[19];
  const float* W_last  = (const float*)d_in[20];
  const float* b_last  = (const float*)d_in[21];
  float* ws  = (float*)d_ws;
  float* out = (float*)d_out;

  // A: 1024 projection blocks + 250 country blocks + 3 code-norm blocks
  kA_fused<<<PROJ_BLOCKS + N_CTRY + 3, 256, 0, stream>>>(
      place, other, doc, W_t2c, b_t2c, W_code, b_code, W_ctx, b_ctx,
      ctab, W_cet, b_cet, code_emb, ws);
  // B: 2048 rows / 4 rows per block
  k3_classify<<<BB / 4, 256, 0, stream>>>(fcodes, ccodes, gaz, W_mix1, b_mix1,
                                          W_mix2, b_mix2, W_last, b_last, ws, out);
}

// Round 4
// 179.917 us; speedup vs baseline: 1.0075x; 1.0075x over previous
//
#include <hip/hip_runtime.h>
#include <math.h>

// Problem dims
#define BB 2048
#define CC 64
#define BERT 768
#define N_CTRY 250
#define N_CODES 654

// ws layout (floats)
#define OFF_PCHAT   0                    // [250][24] normalized country projections
#define OFF_CODEHAT (250*24)             // [654][8]  normalized code embeddings

// ---------------------------------------------------------------------------
// Kernel 1 (tiny): normalized country projections + normalized code rows.
// blocks 0..249: one block per country row. blocks 250..252: code rows.
// ---------------------------------------------------------------------------
__global__ __launch_bounds__(256) void k1_precompute(
    const float* __restrict__ ctab, const float* __restrict__ W_cet,
    const float* __restrict__ b_cet, const float* __restrict__ code_emb,
    float* __restrict__ ws) {
  float* pchat   = ws + OFF_PCHAT;
  float* codehat = ws + OFF_CODEHAT;
  const int bid = blockIdx.x;
  const int tid = threadIdx.x;
  if (bid < N_CTRY) {
    __shared__ float s_proj[24];
    __shared__ float s_inv;
    const int w = tid >> 6, lane = tid & 63;
    const float4* in4 = (const float4*)(ctab + (size_t)bid * BERT);
    float4 xa[3];
#pragma unroll
    for (int i = 0; i < 3; ++i) xa[i] = in4[lane + 64 * i];
    float acc6[6];
#pragma unroll
    for (int jj = 0; jj < 6; ++jj) acc6[jj] = 0.f;
#pragma unroll
    for (int jj = 0; jj < 6; ++jj) {
      const int j = w * 6 + jj;
      const float4* wr = (const float4*)(W_cet + (size_t)j * BERT);
#pragma unroll
      for (int i = 0; i < 3; ++i) {
        float4 wv = wr[lane + 64 * i];
        acc6[jj] += xa[i].x * wv.x + xa[i].y * wv.y + xa[i].z * wv.z + xa[i].w * wv.w;
      }
    }
#pragma unroll
    for (int s = 32; s >= 1; s >>= 1)
#pragma unroll
      for (int jj = 0; jj < 6; ++jj) acc6[jj] += __shfl_xor(acc6[jj], s, 64);
    if (lane == 0) {
#pragma unroll
      for (int jj = 0; jj < 6; ++jj) s_proj[w * 6 + jj] = acc6[jj] + b_cet[w * 6 + jj];
    }
    __syncthreads();
    if (tid == 0) {
      float ss = 0.f;
      for (int k = 0; k < 24; ++k) ss += s_proj[k] * s_proj[k];
      s_inv = 1.f / fmaxf(sqrtf(ss), 1e-8f);
    }
    __syncthreads();
    if (tid < 24) pchat[bid * 24 + tid] = s_proj[tid] * s_inv;
  } else {
    const int idx = (bid - N_CTRY) * 256 + tid;
    if (idx < N_CODES) {
      float v[8];
      float ss = 0.f;
#pragma unroll
      for (int k = 0; k < 8; ++k) { v[k] = code_emb[idx * 8 + k]; ss += v[k] * v[k]; }
      const float inv = 1.f / fmaxf(sqrtf(ss), 1e-8f);
#pragma unroll
      for (int k = 0; k < 8; ++k) codehat[idx * 8 + k] = v[k] * inv;
    }
  }
}

// ---------------------------------------------------------------------------
// Kernel 2 (fused): per-row projections + classify + softmax, one block = 4 rows.
// 512 blocks x 256 threads, exactly 2 blocks/CU -> single dispatch round.
//
// Projection: wave w <-> row w. lane = (kq = lane>>2, jsub = lane&3).
// Each lane: 48-elem interleaved k-strip (k = 4*kq + 64*i), outputs j = 4*jj+jsub.
// Tensor boundaries (j=32 -> jj=8, j=56 -> jj=14) are compile-time in the
// unrolled jj loop -> x-slice (12 float4 in VGPRs) reloaded exactly twice.
// Reduction: 4-stage butterfly over kq only (80 shuffles/wave, was 240).
// Classify: pchat/codehat/gaz staged in LDS (padded strides 25/9), lane=class,
// softmax = one wave butterfly (C=64=wave).
// ---------------------------------------------------------------------------
__global__ __launch_bounds__(256, 2) void k2_fused(
    const float* __restrict__ place, const float* __restrict__ other,
    const float* __restrict__ doc,
    const float* __restrict__ W_t2c, const float* __restrict__ b_t2c,
    const float* __restrict__ W_code, const float* __restrict__ b_code,
    const float* __restrict__ W_ctx, const float* __restrict__ b_ctx,
    const int* __restrict__ fcodes, const int* __restrict__ ccodes,
    const float* __restrict__ gaz,
    const float* __restrict__ W_mix1, const float* __restrict__ b_mix1,
    const float* __restrict__ W_mix2, const float* __restrict__ b_mix2,
    const float* __restrict__ W_last, const float* __restrict__ b_last,
    const float* __restrict__ ws, float* __restrict__ out) {
  __shared__ union {
    float in[12][768];                    // proj phase: 4 rows x 3 tensors, 36 KB
    struct {
      float pch[250 * 25];                // classify: padded country rows, 25 KB
      float cdh[654 * 9];                 // padded code rows, 23.5 KB
      float gz[4 * 64 * 9];               // this block's gaz rows, 9.2 KB
    } c;
  } u;                                    // 57.8 KB
  __shared__ float s_proj[4][80];
  __shared__ float s_inv[4][4];

  const int tid = threadIdx.x;
  const int w = tid >> 6, lane = tid & 63;
  const int row0 = blockIdx.x * 4;
  const int jsub = lane & 3, kq = lane >> 2;

  // ---- stage 12 input rows into LDS, coalesced ----
  float4* s_in4 = (float4*)&u.in[0][0];
  for (int f = tid; f < 2304; f += 256) {
    const int rowi = f / 192, col = f % 192;
    const int t = rowi >> 2, r = rowi & 3;
    const float* bp = (t == 0) ? place : (t == 1) ? other : doc;
    s_in4[f] = ((const float4*)(bp + (size_t)(row0 + r) * BERT))[col];
  }
  __syncthreads();

  // ---- projection: acc[jj] for j = 4*jj + jsub of row w ----
  float acc[20];
  float4 x4[12];
#pragma unroll
  for (int jj = 0; jj < 20; ++jj) {
    if (jj == 0 || jj == 8 || jj == 14) {
      const int t = (jj == 0) ? 0 : (jj == 8) ? 1 : 2;
      const float4* xs = (const float4*)&u.in[t * 4 + w][0];
#pragma unroll
      for (int i = 0; i < 12; ++i) x4[i] = xs[kq + 16 * i];
    }
    const int jbase = 4 * jj;
    const float* wbase;
    int jb;
    if (jbase < 24)      { wbase = W_t2c;  jb = jbase; }
    else if (jbase < 32) { wbase = W_code; jb = jbase - 24; }
    else if (jbase < 56) { wbase = W_ctx;  jb = jbase - 32; }
    else                 { wbase = W_ctx;  jb = jbase - 56; }
    const float4* wr = (const float4*)(wbase + (size_t)(jb + jsub) * BERT);
    float s0 = 0.f, s1 = 0.f, s2 = 0.f, s3 = 0.f;
#pragma unroll
    for (int c = 0; c < 3; ++c) {
      float4 w0 = wr[kq + 16 * (4 * c + 0)];
      float4 w1 = wr[kq + 16 * (4 * c + 1)];
      float4 w2 = wr[kq + 16 * (4 * c + 2)];
      float4 w3 = wr[kq + 16 * (4 * c + 3)];
      s0 += x4[4*c+0].x * w0.x + x4[4*c+0].y * w0.y + x4[4*c+0].z * w0.z + x4[4*c+0].w * w0.w;
      s1 += x4[4*c+1].x * w1.x + x4[4*c+1].y * w1.y + x4[4*c+1].z * w1.z + x4[4*c+1].w * w1.w;
      s2 += x4[4*c+2].x * w2.x + x4[4*c+2].y * w2.y + x4[4*c+2].z * w2.z + x4[4*c+2].w * w2.w;
      s3 += x4[4*c+3].x * w3.x + x4[4*c+3].y * w3.y + x4[4*c+3].z * w3.z + x4[4*c+3].w * w3.w;
    }
    acc[jj] = (s0 + s1) + (s2 + s3);
  }

  // ---- 4-stage butterfly over kq only ----
#pragma unroll
  for (int m = 4; m <= 32; m <<= 1)
#pragma unroll
    for (int jj = 0; jj < 20; ++jj)
      acc[jj] += __shfl_xor(acc[jj], m, 64);
  if (kq == 0) {
#pragma unroll
    for (int jj = 0; jj < 20; ++jj) s_proj[w][4 * jj + jsub] = acc[jj];
  }
  __syncthreads();

  // ---- add biases (raw projections; norms folded in later) ----
  for (int e = tid; e < 320; e += 256) {
    const int j = e % 80;
    const float bias = (j < 24) ? b_t2c[j] : (j < 32) ? b_code[j - 24]
                     : (j < 56) ? b_ctx[j - 32] : b_ctx[j - 56];
    ((float*)s_proj)[e] += bias;
  }
  __syncthreads();

  // ---- inv norms (16 threads) + stage classify tables (all threads) ----
  if (tid < 16) {
    const int r = tid >> 2, g = tid & 3;
    const int st[5] = {0, 24, 32, 56, 80};
    float ss = 0.f;
    for (int k = st[g]; k < st[g + 1]; ++k) ss += s_proj[r][k] * s_proj[r][k];
    s_inv[r][g] = 1.f / fmaxf(sqrtf(ss), 1e-8f);
  }
  {
    const float* wpch = ws + OFF_PCHAT;
    const float* wcdh = ws + OFF_CODEHAT;
    for (int e = tid; e < 6000; e += 256) u.c.pch[(e / 24) * 25 + (e % 24)] = wpch[e];
    for (int e = tid; e < 5232; e += 256) u.c.cdh[(e >> 3) * 9 + (e & 7)] = wcdh[e];
    float4* gz4 = (float4*)u.c.gz;
    const float4* g4 = (const float4*)(gaz + (size_t)row0 * CC * 9);
    for (int e = tid; e < 576; e += 256) gz4[e] = g4[e];
  }
  __syncthreads();

  // ---- classify: wave w -> row row0+w, lane = class ----
  const int row = row0 + w;
  const int cidx = ccodes[row * CC + lane];
  const int fidx = fcodes[row * CC + lane];

  float cc[24];
#pragma unroll
  for (int k = 0; k < 24; ++k) cc[k] = u.c.pch[cidx * 25 + k];
  float cd[8];
#pragma unroll
  for (int k = 0; k < 8; ++k) cd[k] = u.c.cdh[fidx * 9 + k];

  float sc = 0.f, so = 0.f, sd = 0.f, sq = 0.f;
#pragma unroll
  for (int k = 0; k < 24; ++k) {
    const float ck = cc[k];
    sc += s_proj[w][k] * ck;
    so += s_proj[w][32 + k] * ck;
    sd += s_proj[w][56 + k] * ck;
  }
#pragma unroll
  for (int k = 0; k < 8; ++k) sq += s_proj[w][24 + k] * cd[k];

  float f[13];
  f[0] = sc * s_inv[w][0];
  f[1] = sq * s_inv[w][1];
  f[2] = so * s_inv[w][2];
  f[3] = sd * s_inv[w][3];
#pragma unroll
  for (int i = 0; i < 9; ++i) f[4 + i] = u.c.gz[(w * 64 + lane) * 9 + i];

  float h1[24];
#pragma unroll
  for (int j = 0; j < 24; ++j) {
    float a = b_mix1[j];
#pragma unroll
    for (int i = 0; i < 13; ++i) a += W_mix1[j * 13 + i] * f[i];
    h1[j] = 1.f / (1.f + __expf(-a));
  }
  float h2[24];
#pragma unroll
  for (int j = 0; j < 24; ++j) {
    float a = b_mix2[j];
#pragma unroll
    for (int i = 0; i < 24; ++i) a += W_mix2[j * 24 + i] * h1[i];
    h2[j] = 1.f / (1.f + __expf(-a));
  }
  float last = b_last[0];
#pragma unroll
  for (int k = 0; k < 24; ++k) last += W_last[k] * h2[k];

  // softmax across the 64 lanes (classes)
  float mx = last;
#pragma unroll
  for (int s = 32; s >= 1; s >>= 1) mx = fmaxf(mx, __shfl_xor(mx, s, 64));
  const float e = __expf(last - mx);
  float ssum = e;
#pragma unroll
  for (int s = 32; s >= 1; s >>= 1) ssum += __shfl_xor(ssum, s, 64);
  out[row * CC + lane] = e / ssum;
}

// ---------------------------------------------------------------------------
extern "C" void kernel_launch(void* const* d_in, const int* in_sizes, int n_in,
                              void* d_out, int out_size, void* d_ws, size_t ws_size,
                              hipStream_t stream) {
  const float* place   = (const float*)d_in[0];
  const float* other   = (const float*)d_in[1];
  const float* doc     = (const float*)d_in[2];
  const int*   fcodes  = (const int*)d_in[3];
  const int*   ccodes  = (const int*)d_in[4];
  const float* gaz     = (const float*)d_in[5];
  const float* code_emb= (const float*)d_in[6];
  const float* ctab    = (const float*)d_in[7];
  const float* W_cet   = (const float*)d_in[8];
  const float* b_cet   = (const float*)d_in[9];
  const float* W_t2c   = (const float*)d_in[10];
  const float* b_t2c   = (const float*)d_in[11];
  const float* W_ctx   = (const float*)d_in[12];
  const float* b_ctx   = (const float*)d_in[13];
  const float* W_code  = (const float*)d_in[14];
  const float* b_code  = (const float*)d_in[15];
  const float* W_mix1  = (const float*)d_in[16];
  const float* b_mix1  = (const float*)d_in[17];
  const float* W_mix2  = (const float*)d_in[18];
  const float* b_mix2  = (const float*)d_in[19];
  const float* W_last  = (const float*)d_in[20];
  const float* b_last  = (const float*)d_in[21];
  float* ws  = (float*)d_ws;
  float* out = (float*)d_out;

  k1_precompute<<<N_CTRY + 3, 256, 0, stream>>>(ctab, W_cet, b_cet, code_emb, ws);
  k2_fused<<<BB / 4, 256, 0, stream>>>(place, other, doc, W_t2c, b_t2c,
                                       W_code, b_code, W_ctx, b_ctx,
                                       fcodes, ccodes, gaz, W_mix1, b_mix1,
                                       W_mix2, b_mix2, W_last, b_last, ws, out);
}

// Round 5
// 148.058 us; speedup vs baseline: 1.2243x; 1.2152x over previous
//
#include <hip/hip_runtime.h>
#include <math.h>

// Problem dims
#define BB 2048
#define CC 64
#define BERT 768
#define N_CTRY 250
#define N_CODES 654

// ws layout (floats)
#define OFF_PCHAT   0                          // [250][24] normalized country projections
#define OFF_CODEHAT (250*24)                   // [654][8]  normalized code embeddings
#define OFF_XALL    (OFF_CODEHAT + 654*8)      // [2048][80] RAW projections (+bias)
#define OFF_SSQ     (OFF_XALL + 2048*80)       // [2048][10] per-(row,cb) sumsq partials

#define RPB 8                                  // rows streamed per projection block
#define ROWGRPS (BB / RPB)                     // 256
#define PROJ_BLOCKS (5 * ROWGRPS)              // 1280 (5 column-blocks of 16 j's)

// ---------------------------------------------------------------------------
// Kernel 1 (fused grid): projection (weight-stationary, row-streaming) +
// country-table precompute + code-norm precompute.
//
//   blocks [0,1280):  cb = bid/256 owns j in [16cb,16cb+16); wave w owns 4 j's;
//                     lane (kq=lane>>2, jsub=lane&3) owns j = 16cb+4w+jsub with
//                     a 48-elem k-strip. Weights (12 float4) loaded ONCE, then
//                     8 rows streamed: 12 coalesced x-loads + 48 FMA + 4-stage
//                     butterfly + bias -> xall raw; sumsq partials -> ssq.
//                     Group boundaries (j=24,32,56) align to wave boundaries.
//   blocks [1280,1530): country rows -> pchat (normalized)
//   blocks [1530,1533): code rows -> codehat (normalized)
// ---------------------------------------------------------------------------
__global__ __launch_bounds__(256) void k_proj(
    const float* __restrict__ place, const float* __restrict__ other,
    const float* __restrict__ doc,
    const float* __restrict__ W_t2c, const float* __restrict__ b_t2c,
    const float* __restrict__ W_code, const float* __restrict__ b_code,
    const float* __restrict__ W_ctx, const float* __restrict__ b_ctx,
    const float* __restrict__ ctab, const float* __restrict__ W_cet,
    const float* __restrict__ b_cet, const float* __restrict__ code_emb,
    float* __restrict__ ws) {
  __shared__ float s_ss[RPB][4];
  __shared__ float s_p24[24];
  __shared__ float s_inv1;

  const int bid = blockIdx.x;
  const int tid = threadIdx.x;
  const int w = tid >> 6, lane = tid & 63;

  if (bid < PROJ_BLOCKS) {
    float* xall = ws + OFF_XALL;
    float* ssq  = ws + OFF_SSQ;
    const int cb = bid / ROWGRPS;              // 0..4 (column block)
    const int rg = bid % ROWGRPS;
    const int row0 = rg * RPB;
    const int j0 = cb * 16 + w * 4;            // wave-uniform base j
    const float* wbase; const float* xbase; const float* bbase; int jb;
    if (j0 < 24)      { wbase = W_t2c;  bbase = b_t2c;  jb = j0;      xbase = place; }
    else if (j0 < 32) { wbase = W_code; bbase = b_code; jb = j0 - 24; xbase = place; }
    else if (j0 < 56) { wbase = W_ctx;  bbase = b_ctx;  jb = j0 - 32; xbase = other; }
    else              { wbase = W_ctx;  bbase = b_ctx;  jb = j0 - 56; xbase = doc;   }
    const int jsub = lane & 3, kq = lane >> 2;
    const float bias = bbase[jb + jsub];

    // stationary weights: this lane's j-row strip (12 float4 = 48 VGPR)
    float4 wv[12];
    {
      const float4* wr = (const float4*)(wbase + (size_t)(jb + jsub) * BERT);
#pragma unroll
      for (int i = 0; i < 12; ++i) wv[i] = wr[kq + 16 * i];
    }

    for (int r = 0; r < RPB; ++r) {
      const int row = row0 + r;
      const float4* xr = (const float4*)(xbase + (size_t)row * BERT);
      float s0 = 0.f, s1 = 0.f, s2 = 0.f, s3 = 0.f;
#pragma unroll
      for (int i = 0; i < 12; i += 4) {
        float4 a0 = xr[kq + 16 * (i + 0)];
        float4 a1 = xr[kq + 16 * (i + 1)];
        float4 a2 = xr[kq + 16 * (i + 2)];
        float4 a3 = xr[kq + 16 * (i + 3)];
        s0 += a0.x * wv[i+0].x + a0.y * wv[i+0].y + a0.z * wv[i+0].z + a0.w * wv[i+0].w;
        s1 += a1.x * wv[i+1].x + a1.y * wv[i+1].y + a1.z * wv[i+1].z + a1.w * wv[i+1].w;
        s2 += a2.x * wv[i+2].x + a2.y * wv[i+2].y + a2.z * wv[i+2].z + a2.w * wv[i+2].w;
        s3 += a3.x * wv[i+3].x + a3.y * wv[i+3].y + a3.z * wv[i+3].z + a3.w * wv[i+3].w;
      }
      float acc = (s0 + s1) + (s2 + s3);
      // butterfly over kq bits only (jsub preserved) -> every lane has its j total
#pragma unroll
      for (int m = 4; m <= 32; m <<= 1) acc += __shfl_xor(acc, m, 64);
      const float val = acc + bias;
      if (kq == 0) xall[(size_t)row * 80 + j0 + jsub] = val;   // 16B contiguous
      // sumsq over this wave's 4 j's (post-bias)
      float v2 = val * val;
      v2 += __shfl_xor(v2, 1, 64);
      v2 += __shfl_xor(v2, 2, 64);
      if (lane == 0) s_ss[r][w] = v2;
    }
    __syncthreads();
    if (tid < RPB * 2) {
      const int r = tid >> 1, s = tid & 1;   // s=0: waves 0,1  s=1: waves 2,3
      ssq[(size_t)(row0 + r) * 10 + cb * 2 + s] = s_ss[r][2 * s] + s_ss[r][2 * s + 1];
    }
  } else if (bid < PROJ_BLOCKS + N_CTRY) {
    // ---------------- country-table projection path ----------------
    float* pchat = ws + OFF_PCHAT;
    const int b = bid - PROJ_BLOCKS;
    float4 xa[3];
#pragma unroll
    for (int i = 0; i < 3; ++i)
      xa[i] = ((const float4*)(ctab + (size_t)b * BERT))[lane + 64 * i];
    float acc6[6];
#pragma unroll
    for (int jj = 0; jj < 6; ++jj) acc6[jj] = 0.f;
#pragma unroll
    for (int jj = 0; jj < 6; ++jj) {
      const int j = w * 6 + jj;
      const float4* wr = (const float4*)(W_cet + (size_t)j * BERT);
#pragma unroll
      for (int i = 0; i < 3; ++i) {
        float4 wv = wr[lane + 64 * i];
        acc6[jj] += xa[i].x * wv.x + xa[i].y * wv.y + xa[i].z * wv.z + xa[i].w * wv.w;
      }
    }
#pragma unroll
    for (int s = 32; s >= 1; s >>= 1)
#pragma unroll
      for (int jj = 0; jj < 6; ++jj) acc6[jj] += __shfl_xor(acc6[jj], s, 64);
    if (lane == 0) {
#pragma unroll
      for (int jj = 0; jj < 6; ++jj) s_p24[w * 6 + jj] = acc6[jj] + b_cet[w * 6 + jj];
    }
    __syncthreads();
    if (tid == 0) {
      float ss = 0.f;
      for (int k = 0; k < 24; ++k) ss += s_p24[k] * s_p24[k];
      s_inv1 = 1.f / fmaxf(sqrtf(ss), 1e-8f);
    }
    __syncthreads();
    if (tid < 24) pchat[b * 24 + tid] = s_p24[tid] * s_inv1;
  } else {
    // ---------------- code-embedding normalization path ----------------
    float* codehat = ws + OFF_CODEHAT;
    const int idx = (bid - PROJ_BLOCKS - N_CTRY) * 256 + tid;
    if (idx < N_CODES) {
      float v[8];
      float ss = 0.f;
#pragma unroll
      for (int k = 0; k < 8; ++k) { v[k] = code_emb[idx * 8 + k]; ss += v[k] * v[k]; }
      const float inv = 1.f / fmaxf(sqrtf(ss), 1e-8f);
#pragma unroll
      for (int k = 0; k < 8; ++k) codehat[idx * 8 + k] = v[k] * inv;
    }
  }
}

// ---------------------------------------------------------------------------
// Kernel 2: classify. 128 threads = 2 waves = 2 rows; lane = class.
// pchat staged in LDS (padded stride 25); codehat gathered from L1/L2;
// xv/ssq via wave-uniform scalar loads; softmax = one wave butterfly.
// LDS ~29.6 KB -> 5 blocks/CU -> 10 waves/CU.
// ---------------------------------------------------------------------------
__global__ __launch_bounds__(128) void k_classify(
    const int* __restrict__ fcodes, const int* __restrict__ ccodes,
    const float* __restrict__ gaz,
    const float* __restrict__ W_mix1, const float* __restrict__ b_mix1,
    const float* __restrict__ W_mix2, const float* __restrict__ b_mix2,
    const float* __restrict__ W_last, const float* __restrict__ b_last,
    const float* __restrict__ ws, float* __restrict__ out) {
  __shared__ float s_pch[N_CTRY * 25];     // 25 KB padded
  __shared__ float s_gz[2 * CC * 9];       // 4.6 KB
  const int tid = threadIdx.x;
  const int w = tid >> 6, lane = tid & 63;
  const int row0 = blockIdx.x * 2;

  {
    const float* pch = ws + OFF_PCHAT;
    for (int e = tid; e < N_CTRY * 24; e += 128)
      s_pch[(e / 24) * 25 + (e % 24)] = pch[e];
    float4* gz4 = (float4*)s_gz;
    const float4* g4 = (const float4*)(gaz + (size_t)row0 * CC * 9);
    for (int e = tid; e < 2 * CC * 9 / 4; e += 128) gz4[e] = g4[e];
  }
  __syncthreads();

  const int row = __builtin_amdgcn_readfirstlane(row0 + w);
  const float* xv = ws + OFF_XALL + (size_t)row * 80;   // uniform -> s_load
  const float* q  = ws + OFF_SSQ + (size_t)row * 10;    // uniform -> s_load
  const float g0 = q[0] + q[1] + q[2];
  const float g1 = q[3];
  const float g2 = q[4] + q[5] + q[6];
  const float g3 = q[7] + q[8] + q[9];
  const float inv0 = 1.f / fmaxf(sqrtf(g0), 1e-8f);
  const float inv1 = 1.f / fmaxf(sqrtf(g1), 1e-8f);
  const float inv2 = 1.f / fmaxf(sqrtf(g2), 1e-8f);
  const float inv3 = 1.f / fmaxf(sqrtf(g3), 1e-8f);

  const int cidx = ccodes[row * CC + lane];
  const int fidx = fcodes[row * CC + lane];

  float cc[24];
#pragma unroll
  for (int k = 0; k < 24; ++k) cc[k] = s_pch[cidx * 25 + k];
  float cd[8];
  {
    const float4* q4 = (const float4*)(ws + OFF_CODEHAT + fidx * 8);
#pragma unroll
    for (int i = 0; i < 2; ++i) {
      float4 v = q4[i];
      cd[4*i+0] = v.x; cd[4*i+1] = v.y; cd[4*i+2] = v.z; cd[4*i+3] = v.w;
    }
  }

  float sc = 0.f, so = 0.f, sd = 0.f, sq = 0.f;
#pragma unroll
  for (int k = 0; k < 24; ++k) {
    const float ck = cc[k];
    sc += xv[k] * ck;
    so += xv[32 + k] * ck;
    sd += xv[56 + k] * ck;
  }
#pragma unroll
  for (int k = 0; k < 8; ++k) sq += xv[24 + k] * cd[k];

  float f[13];
  f[0] = sc * inv0;
  f[1] = sq * inv1;
  f[2] = so * inv2;
  f[3] = sd * inv3;
#pragma unroll
  for (int i = 0; i < 9; ++i) f[4 + i] = s_gz[(w * CC + lane) * 9 + i];

  float h1[24];
#pragma unroll
  for (int j = 0; j < 24; ++j) {
    float a = b_mix1[j];
#pragma unroll
    for (int i = 0; i < 13; ++i) a += W_mix1[j * 13 + i] * f[i];
    h1[j] = 1.f / (1.f + __expf(-a));
  }
  float h2[24];
#pragma unroll
  for (int j = 0; j < 24; ++j) {
    float a = b_mix2[j];
#pragma unroll
    for (int i = 0; i < 24; ++i) a += W_mix2[j * 24 + i] * h1[i];
    h2[j] = 1.f / (1.f + __expf(-a));
  }
  float last = b_last[0];
#pragma unroll
  for (int k = 0; k < 24; ++k) last += W_last[k] * h2[k];

  float mx = last;
#pragma unroll
  for (int s = 32; s >= 1; s >>= 1) mx = fmaxf(mx, __shfl_xor(mx, s, 64));
  const float e = __expf(last - mx);
  float ssum = e;
#pragma unroll
  for (int s = 32; s >= 1; s >>= 1) ssum += __shfl_xor(ssum, s, 64);
  out[row * CC + lane] = e / ssum;
}

// ---------------------------------------------------------------------------
extern "C" void kernel_launch(void* const* d_in, const int* in_sizes, int n_in,
                              void* d_out, int out_size, void* d_ws, size_t ws_size,
                              hipStream_t stream) {
  const float* place   = (const float*)d_in[0];
  const float* other   = (const float*)d_in[1];
  const float* doc     = (const float*)d_in[2];
  const int*   fcodes  = (const int*)d_in[3];
  const int*   ccodes  = (const int*)d_in[4];
  const float* gaz     = (const float*)d_in[5];
  const float* code_emb= (const float*)d_in[6];
  const float* ctab    = (const float*)d_in[7];
  const float* W_cet   = (const float*)d_in[8];
  const float* b_cet   = (const float*)d_in[9];
  const float* W_t2c   = (const float*)d_in[10];
  const float* b_t2c   = (const float*)d_in[11];
  const float* W_ctx   = (const float*)d_in[12];
  const float* b_ctx   = (const float*)d_in[13];
  const float* W_code  = (const float*)d_in[14];
  const float* b_code  = (const float*)d_in[15];
  const float* W_mix1  = (const float*)d_in[16];
  const float* b_mix1  = (const float*)d_in[17];
  const float* W_mix2  = (const float*)d_in[18];
  const float* b_mix2  = (const float*)d_in[19];
  const float* W_last  = (const float*)d_in[20];
  const float* b_last  = (const float*)d_in[21];
  float* ws  = (float*)d_ws;
  float* out = (float*)d_out;

  // proj (1280) + country (250) + code-norm (3) in one grid
  k_proj<<<PROJ_BLOCKS + N_CTRY + 3, 256, 0, stream>>>(
      place, other, doc, W_t2c, b_t2c, W_code, b_code, W_ctx, b_ctx,
      ctab, W_cet, b_cet, code_emb, ws);
  // classify: 2 rows/block
  k_classify<<<BB / 2, 128, 0, stream>>>(fcodes, ccodes, gaz, W_mix1, b_mix1,
                                         W_mix2, b_mix2, W_last, b_last, ws, out);
}

// Round 6
// 143.399 us; speedup vs baseline: 1.2641x; 1.0325x over previous
//
#include <hip/hip_runtime.h>
#include <math.h>

// Problem dims
#define BB 2048
#define CC 64
#define BERT 768
#define N_CTRY 250
#define N_CODES 654

// ws layout (floats)
#define OFF_PCHAT   0                          // [250][24] normalized country projections
#define OFF_CODEHAT (250*24)                   // [654][8]  normalized code embeddings
#define OFF_XALL    (OFF_CODEHAT + 654*8)      // [2048][80] RAW projections (+bias)
#define OFF_SSQ     (OFF_XALL + 2048*80)       // [2048][10] per-(row,cb) sumsq partials

#define RPB 8                                  // rows streamed per projection block
#define ROWGRPS (BB / RPB)                     // 256
#define PROJ_BLOCKS (5 * ROWGRPS)              // 1280 (5 column-blocks of 16 j's)

// ---------------------------------------------------------------------------
// Kernel 1 (fused grid): projection (weight-stationary, row-streaming,
// BATCHED reduction) + country-table precompute + code-norm precompute.
//
//   blocks [0,1280):  cb = bid/256 owns j in [16cb,16cb+16); wave w owns 4 j's;
//                     lane (kq=lane>>2, jsub=lane&3) owns j = 16cb+4w+jsub with
//                     a 48-elem k-strip. Weights (12 float4) loaded ONCE.
//                     Phase 1: 8 rows x 48 FMA -> acc[8] (independent chains).
//                     Phase 2: ONE batched 4-stage butterfly over all 8 accs
//                     (R5 post-mortem: per-row serial butterflies were the
//                     remaining latency chain; batched = 8 indep chains).
//   blocks [1280,1530): country rows -> pchat (normalized)
//   blocks [1530,1533): code rows -> codehat (normalized)
// ---------------------------------------------------------------------------
__global__ __launch_bounds__(256) void k_proj(
    const float* __restrict__ place, const float* __restrict__ other,
    const float* __restrict__ doc,
    const float* __restrict__ W_t2c, const float* __restrict__ b_t2c,
    const float* __restrict__ W_code, const float* __restrict__ b_code,
    const float* __restrict__ W_ctx, const float* __restrict__ b_ctx,
    const float* __restrict__ ctab, const float* __restrict__ W_cet,
    const float* __restrict__ b_cet, const float* __restrict__ code_emb,
    float* __restrict__ ws) {
  __shared__ float s_ss[RPB][4];
  __shared__ float s_p24[24];
  __shared__ float s_inv1;

  const int bid = blockIdx.x;
  const int tid = threadIdx.x;
  const int w = tid >> 6, lane = tid & 63;

  if (bid < PROJ_BLOCKS) {
    float* xall = ws + OFF_XALL;
    float* ssq  = ws + OFF_SSQ;
    const int cb = bid / ROWGRPS;              // 0..4 (column block)
    const int rg = bid % ROWGRPS;
    const int row0 = rg * RPB;
    const int j0 = cb * 16 + w * 4;            // wave-uniform base j
    const float* wbase; const float* xbase; const float* bbase; int jb;
    if (j0 < 24)      { wbase = W_t2c;  bbase = b_t2c;  jb = j0;      xbase = place; }
    else if (j0 < 32) { wbase = W_code; bbase = b_code; jb = j0 - 24; xbase = place; }
    else if (j0 < 56) { wbase = W_ctx;  bbase = b_ctx;  jb = j0 - 32; xbase = other; }
    else              { wbase = W_ctx;  bbase = b_ctx;  jb = j0 - 56; xbase = doc;   }
    const int jsub = lane & 3, kq = lane >> 2;
    const float bias = bbase[jb + jsub];

    // stationary weights: this lane's j-row strip (12 float4 = 48 VGPR)
    float4 wv[12];
    {
      const float4* wr = (const float4*)(wbase + (size_t)(jb + jsub) * BERT);
#pragma unroll
      for (int i = 0; i < 12; ++i) wv[i] = wr[kq + 16 * i];
    }

    // phase 1: independent per-row dot-partials
    float acc[RPB];
#pragma unroll
    for (int r = 0; r < RPB; ++r) {
      const float4* xr = (const float4*)(xbase + (size_t)(row0 + r) * BERT);
      float s0 = 0.f, s1 = 0.f, s2 = 0.f, s3 = 0.f;
#pragma unroll
      for (int i = 0; i < 12; i += 4) {
        float4 a0 = xr[kq + 16 * (i + 0)];
        float4 a1 = xr[kq + 16 * (i + 1)];
        float4 a2 = xr[kq + 16 * (i + 2)];
        float4 a3 = xr[kq + 16 * (i + 3)];
        s0 += a0.x * wv[i+0].x + a0.y * wv[i+0].y + a0.z * wv[i+0].z + a0.w * wv[i+0].w;
        s1 += a1.x * wv[i+1].x + a1.y * wv[i+1].y + a1.z * wv[i+1].z + a1.w * wv[i+1].w;
        s2 += a2.x * wv[i+2].x + a2.y * wv[i+2].y + a2.z * wv[i+2].z + a2.w * wv[i+2].w;
        s3 += a3.x * wv[i+3].x + a3.y * wv[i+3].y + a3.z * wv[i+3].z + a3.w * wv[i+3].w;
      }
      acc[r] = (s0 + s1) + (s2 + s3);
    }

    // phase 2: ONE batched butterfly over kq bits (8 independent chains)
#pragma unroll
    for (int m = 4; m <= 32; m <<= 1)
#pragma unroll
      for (int r = 0; r < RPB; ++r) acc[r] += __shfl_xor(acc[r], m, 64);

    // bias, store, batched sumsq
    float v2[RPB];
#pragma unroll
    for (int r = 0; r < RPB; ++r) {
      const float val = acc[r] + bias;
      if (kq == 0) xall[(size_t)(row0 + r) * 80 + j0 + jsub] = val;
      v2[r] = val * val;
    }
#pragma unroll
    for (int r = 0; r < RPB; ++r) v2[r] += __shfl_xor(v2[r], 1, 64);
#pragma unroll
    for (int r = 0; r < RPB; ++r) v2[r] += __shfl_xor(v2[r], 2, 64);
    if (lane == 0) {
#pragma unroll
      for (int r = 0; r < RPB; ++r) s_ss[r][w] = v2[r];
    }
    __syncthreads();
    if (tid < RPB * 2) {
      const int r = tid >> 1, s = tid & 1;   // s=0: waves 0,1  s=1: waves 2,3
      ssq[(size_t)(row0 + r) * 10 + cb * 2 + s] = s_ss[r][2 * s] + s_ss[r][2 * s + 1];
    }
  } else if (bid < PROJ_BLOCKS + N_CTRY) {
    // ---------------- country-table projection path ----------------
    float* pchat = ws + OFF_PCHAT;
    const int b = bid - PROJ_BLOCKS;
    float4 xa[3];
#pragma unroll
    for (int i = 0; i < 3; ++i)
      xa[i] = ((const float4*)(ctab + (size_t)b * BERT))[lane + 64 * i];
    float acc6[6];
#pragma unroll
    for (int jj = 0; jj < 6; ++jj) acc6[jj] = 0.f;
#pragma unroll
    for (int jj = 0; jj < 6; ++jj) {
      const int j = w * 6 + jj;
      const float4* wr = (const float4*)(W_cet + (size_t)j * BERT);
#pragma unroll
      for (int i = 0; i < 3; ++i) {
        float4 wvv = wr[lane + 64 * i];
        acc6[jj] += xa[i].x * wvv.x + xa[i].y * wvv.y + xa[i].z * wvv.z + xa[i].w * wvv.w;
      }
    }
#pragma unroll
    for (int s = 32; s >= 1; s >>= 1)
#pragma unroll
      for (int jj = 0; jj < 6; ++jj) acc6[jj] += __shfl_xor(acc6[jj], s, 64);
    if (lane == 0) {
#pragma unroll
      for (int jj = 0; jj < 6; ++jj) s_p24[w * 6 + jj] = acc6[jj] + b_cet[w * 6 + jj];
    }
    __syncthreads();
    if (tid == 0) {
      float ss = 0.f;
      for (int k = 0; k < 24; ++k) ss += s_p24[k] * s_p24[k];
      s_inv1 = 1.f / fmaxf(sqrtf(ss), 1e-8f);
    }
    __syncthreads();
    if (tid < 24) pchat[b * 24 + tid] = s_p24[tid] * s_inv1;
  } else {
    // ---------------- code-embedding normalization path ----------------
    float* codehat = ws + OFF_CODEHAT;
    const int idx = (bid - PROJ_BLOCKS - N_CTRY) * 256 + tid;
    if (idx < N_CODES) {
      float v[8];
      float ss = 0.f;
#pragma unroll
      for (int k = 0; k < 8; ++k) { v[k] = code_emb[idx * 8 + k]; ss += v[k] * v[k]; }
      const float inv = 1.f / fmaxf(sqrtf(ss), 1e-8f);
#pragma unroll
      for (int k = 0; k < 8; ++k) codehat[idx * 8 + k] = v[k] * inv;
    }
  }
}

// ---------------------------------------------------------------------------
// Kernel 2: classify. 256 threads = 4 waves = 4 rows; lane = class.
// pchat staged in LDS (padded stride 25; 512 blocks halves staging traffic
// vs R5's 1024). codehat + gaz gathered directly (L1/L2-resident);
// xv/ssq wave-uniform scalar loads; softmax = one wave butterfly.
// ---------------------------------------------------------------------------
__global__ __launch_bounds__(256) void k_classify(
    const int* __restrict__ fcodes, const int* __restrict__ ccodes,
    const float* __restrict__ gaz,
    const float* __restrict__ W_mix1, const float* __restrict__ b_mix1,
    const float* __restrict__ W_mix2, const float* __restrict__ b_mix2,
    const float* __restrict__ W_last, const float* __restrict__ b_last,
    const float* __restrict__ ws, float* __restrict__ out) {
  __shared__ float s_pch[N_CTRY * 25];     // 25 KB padded
  const int tid = threadIdx.x;
  const int w = tid >> 6, lane = tid & 63;
  const int row0 = blockIdx.x * 4;

  {
    const float* pch = ws + OFF_PCHAT;
    for (int e = tid; e < N_CTRY * 24; e += 256)
      s_pch[(e / 24) * 25 + (e % 24)] = pch[e];
  }
  __syncthreads();

  const int row = __builtin_amdgcn_readfirstlane(row0 + w);
  const float* xv = ws + OFF_XALL + (size_t)row * 80;   // uniform -> s_load
  const float* q  = ws + OFF_SSQ + (size_t)row * 10;    // uniform -> s_load
  const float g0 = q[0] + q[1] + q[2];
  const float g1 = q[3];
  const float g2 = q[4] + q[5] + q[6];
  const float g3 = q[7] + q[8] + q[9];
  const float inv0 = 1.f / fmaxf(sqrtf(g0), 1e-8f);
  const float inv1 = 1.f / fmaxf(sqrtf(g1), 1e-8f);
  const float inv2 = 1.f / fmaxf(sqrtf(g2), 1e-8f);
  const float inv3 = 1.f / fmaxf(sqrtf(g3), 1e-8f);

  const int cidx = ccodes[row * CC + lane];
  const int fidx = fcodes[row * CC + lane];

  float cc[24];
#pragma unroll
  for (int k = 0; k < 24; ++k) cc[k] = s_pch[cidx * 25 + k];
  float cd[8];
  {
    const float4* q4 = (const float4*)(ws + OFF_CODEHAT + fidx * 8);
#pragma unroll
    for (int i = 0; i < 2; ++i) {
      float4 v = q4[i];
      cd[4*i+0] = v.x; cd[4*i+1] = v.y; cd[4*i+2] = v.z; cd[4*i+3] = v.w;
    }
  }

  float sc = 0.f, so = 0.f, sd = 0.f, sq = 0.f;
#pragma unroll
  for (int k = 0; k < 24; ++k) {
    const float ck = cc[k];
    sc += xv[k] * ck;
    so += xv[32 + k] * ck;
    sd += xv[56 + k] * ck;
  }
#pragma unroll
  for (int k = 0; k < 8; ++k) sq += xv[24 + k] * cd[k];

  float f[13];
  f[0] = sc * inv0;
  f[1] = sq * inv1;
  f[2] = so * inv2;
  f[3] = sd * inv3;
  {
    const float* g = gaz + (size_t)(row * CC + lane) * 9;
    float4 ga = ((const float4*)g)[0];
    float4 gb = ((const float4*)g)[1];
    f[4] = ga.x; f[5] = ga.y; f[6] = ga.z; f[7] = ga.w;
    f[8] = gb.x; f[9] = gb.y; f[10] = gb.z; f[11] = gb.w;
    f[12] = g[8];
  }

  float h1[24];
#pragma unroll
  for (int j = 0; j < 24; ++j) {
    float a = b_mix1[j];
#pragma unroll
    for (int i = 0; i < 13; ++i) a += W_mix1[j * 13 + i] * f[i];
    h1[j] = 1.f / (1.f + __expf(-a));
  }
  float h2[24];
#pragma unroll
  for (int j = 0; j < 24; ++j) {
    float a = b_mix2[j];
#pragma unroll
    for (int i = 0; i < 24; ++i) a += W_mix2[j * 24 + i] * h1[i];
    h2[j] = 1.f / (1.f + __expf(-a));
  }
  float last = b_last[0];
#pragma unroll
  for (int k = 0; k < 24; ++k) last += W_last[k] * h2[k];

  float mx = last;
#pragma unroll
  for (int s = 32; s >= 1; s >>= 1) mx = fmaxf(mx, __shfl_xor(mx, s, 64));
  const float e = __expf(last - mx);
  float ssum = e;
#pragma unroll
  for (int s = 32; s >= 1; s >>= 1) ssum += __shfl_xor(ssum, s, 64);
  out[row * CC + lane] = e / ssum;
}

// ---------------------------------------------------------------------------
extern "C" void kernel_launch(void* const* d_in, const int* in_sizes, int n_in,
                              void* d_out, int out_size, void* d_ws, size_t ws_size,
                              hipStream_t stream) {
  const float* place   = (const float*)d_in[0];
  const float* other   = (const float*)d_in[1];
  const float* doc     = (const float*)d_in[2];
  const int*   fcodes  = (const int*)d_in[3];
  const int*   ccodes  = (const int*)d_in[4];
  const float* gaz     = (const float*)d_in[5];
  const float* code_emb= (const float*)d_in[6];
  const float* ctab    = (const float*)d_in[7];
  const float* W_cet   = (const float*)d_in[8];
  const float* b_cet   = (const float*)d_in[9];
  const float* W_t2c   = (const float*)d_in[10];
  const float* b_t2c   = (const float*)d_in[11];
  const float* W_ctx   = (const float*)d_in[12];
  const float* b_ctx   = (const float*)d_in[13];
  const float* W_code  = (const float*)d_in[14];
  const float* b_code  = (const float*)d_in[15];
  const float* W_mix1  = (const float*)d_in[16];
  const float* b_mix1  = (const float*)d_in[17];
  const float* W_mix2  = (const float*)d_in[18];
  const float* b_mix2  = (const float*)d_in[19];
  const float* W_last  = (const float*)d_in[20];
  const float* b_last  = (const float*)d_in[21];
  float* ws  = (float*)d_ws;
  float* out = (float*)d_out;

  // proj (1280) + country (250) + code-norm (3) in one grid
  k_proj<<<PROJ_BLOCKS + N_CTRY + 3, 256, 0, stream>>>(
      place, other, doc, W_t2c, b_t2c, W_code, b_code, W_ctx, b_ctx,
      ctab, W_cet, b_cet, code_emb, ws);
  // classify: 4 rows/block
  k_classify<<<BB / 4, 256, 0, stream>>>(fcodes, ccodes, gaz, W_mix1, b_mix1,
                                         W_mix2, b_mix2, W_last, b_last, ws, out);
}